// Round 2
// baseline (166.488 us; speedup 1.0000x reference)
//
#include <hip/hip_runtime.h>

#define U_N 100000
#define I_N 100000
#define D_N 64
#define B_N 16384
#define T_N 1638400
#define R_N 5

// ---------------------------------------------------------------------------
// Kernel 1: rowsum[i] = sum over D of Mr[i][:].  16 threads per row, each
// loading one float4 (wave reads 1 KB contiguous = 4 rows), xor-shuffle
// reduce within the 16-lane group, sub-lane 0 writes.
// ---------------------------------------------------------------------------
__global__ void rowsum_kernel(const float* __restrict__ Mr, float* __restrict__ rowsum) {
    int tid = blockIdx.x * blockDim.x + threadIdx.x;      // I_N*16 threads
    int row = tid >> 4;
    int sub = tid & 15;
    if (row >= I_N) return;
    const float4* p = (const float4*)(Mr + (long)row * D_N);
    float4 v4 = p[sub];
    float v = v4.x + v4.y + v4.z + v4.w;
    // xor masks 1,2,4,8 stay within the 16-lane group at width 64
    v += __shfl_xor(v, 1);
    v += __shfl_xor(v, 2);
    v += __shfl_xor(v, 4);
    v += __shfl_xor(v, 8);
    if (sub == 0) rowsum[row] = v;
}

// ---------------------------------------------------------------------------
// Kernel 2: fused per-sample kernel. One wave per sample.
//   - binary search the sorted seg_ids for this sample's contiguous range
//   - accumulate per-rating (5) sums/counts via LDS atomics
//   - compute uu = sum_r seg_sum_r / sqrt(cnt_r)
//   - final: dot(ue,ie) + uu*sum(ie) + biases + global_avg, clipped
// No global atomics, no workspace besides rowsum.
// ---------------------------------------------------------------------------
__device__ __forceinline__ int lower_bound_i(const int* __restrict__ a, int n, int val) {
    int lo = 0, hi = n;
    while (lo < hi) {
        int mid = (lo + hi) >> 1;
        if (a[mid] < val) lo = mid + 1; else hi = mid;
    }
    return lo;
}

__global__ void sample_kernel(const int* __restrict__ user_idx,
                              const int* __restrict__ item_idx,
                              const int* __restrict__ flat_items,
                              const int* __restrict__ seg_ids,
                              const float* __restrict__ user_emb,
                              const float* __restrict__ item_emb,
                              const float* __restrict__ user_bias,
                              const float* __restrict__ item_bias,
                              const float* __restrict__ global_avg,
                              const float* __restrict__ rowsum,
                              float* __restrict__ out) {
    __shared__ float s_sum[4][5];
    __shared__ int   s_cnt[4][5];

    int w    = threadIdx.x >> 6;     // wave within block (4 waves)
    int lane = threadIdx.x & 63;
    int b    = blockIdx.x * 4 + w;   // sample id
    if (b >= B_N) return;

    if (lane < R_N) { s_sum[w][lane] = 0.f; s_cnt[w][lane] = 0; }
    __syncthreads();

    // all lanes compute the range redundantly (broadcast loads, L2-cached)
    int lo = lower_bound_i(seg_ids, T_N, b * R_N);
    int hi = lower_bound_i(seg_ids, T_N, b * R_N + R_N);
    int target = item_idx[b];

    for (int t = lo + lane; t < hi; t += 64) {
        int sg = seg_ids[t];
        int it = flat_items[t];
        if (it != target) {
            int r = sg - b * R_N;
            atomicAdd(&s_sum[w][r], rowsum[it]);
            atomicAdd(&s_cnt[w][r], 1);
        }
    }
    __syncthreads();

    float uu = 0.f;
    if (lane == 0) {
        #pragma unroll
        for (int r = 0; r < R_N; ++r) {
            int c = s_cnt[w][r];
            if (c > 0) uu += s_sum[w][r] / sqrtf((float)c);
        }
    }

    int u = user_idx[b];
    float ue = user_emb[(long)u * D_N + lane];
    float ie = item_emb[(long)target * D_N + lane];
    float dot = ue * ie;
    float isum = ie;
    #pragma unroll
    for (int off = 32; off >= 1; off >>= 1) {
        dot  += __shfl_xor(dot, off);
        isum += __shfl_xor(isum, off);
    }
    if (lane == 0) {
        float rui = dot + uu * isum + user_bias[u] + item_bias[target] + global_avg[0];
        rui = fminf(fmaxf(rui, 1.0f), 5.0f);
        out[b] = rui;
    }
}

extern "C" void kernel_launch(void* const* d_in, const int* in_sizes, int n_in,
                              void* d_out, int out_size, void* d_ws, size_t ws_size,
                              hipStream_t stream) {
    const int*   user_idx   = (const int*)d_in[0];
    const int*   item_idx   = (const int*)d_in[1];
    const int*   flat_items = (const int*)d_in[2];
    const int*   seg_ids    = (const int*)d_in[3];
    const float* user_emb   = (const float*)d_in[4];
    const float* item_emb   = (const float*)d_in[5];
    const float* Mr         = (const float*)d_in[6];
    const float* user_bias  = (const float*)d_in[7];
    const float* item_bias  = (const float*)d_in[8];
    const float* global_avg = (const float*)d_in[9];
    float* out = (float*)d_out;

    float* rowsum = (float*)d_ws;   // I_N floats

    rowsum_kernel<<<(I_N * 16 + 255) / 256, 256, 0, stream>>>(Mr, rowsum);
    sample_kernel<<<B_N / 4, 256, 0, stream>>>(
        user_idx, item_idx, flat_items, seg_ids, user_emb, item_emb,
        user_bias, item_bias, global_avg, rowsum, out);
}

// Round 3
// 147.283 us; speedup vs baseline: 1.1304x; 1.1304x over previous
//
#include <hip/hip_runtime.h>

#define U_N 100000
#define I_N 100000
#define D_N 64
#define B_N 16384
#define T_N 1638400
#define R_N 5

#define RS_THREADS (I_N * 16)    // rowsum part: 16 threads/row
#define BD_THREADS (T_N / 4)     // boundary part: 4 elements/thread
#define K1_THREADS (RS_THREADS + BD_THREADS)

// ---------------------------------------------------------------------------
// Kernel 1 (fused): (a) rowsum[i] = sum_d Mr[i][d]; (b) scatter sample range
// starts: sample_start[b] = first t with seg_ids[t] >= 5b. Sorted seg_ids =>
// a linear transition scan finds every boundary; avg 1 boundary per 100
// elements so the inner gap loop is nearly always empty.
// ---------------------------------------------------------------------------
__global__ void prep_kernel(const float* __restrict__ Mr,
                            const int* __restrict__ seg_ids,
                            float* __restrict__ rowsum,
                            int* __restrict__ sample_start) {
    int gtid = blockIdx.x * blockDim.x + threadIdx.x;
    if (gtid < RS_THREADS) {
        int row = gtid >> 4;
        int sub = gtid & 15;
        const float4* p = (const float4*)(Mr + (long)row * D_N);
        float4 v4 = p[sub];
        float v = v4.x + v4.y + v4.z + v4.w;
        v += __shfl_xor(v, 1);
        v += __shfl_xor(v, 2);
        v += __shfl_xor(v, 4);
        v += __shfl_xor(v, 8);
        if (sub == 0) rowsum[row] = v;
    } else {
        int t4 = gtid - RS_THREADS;
        if (t4 >= BD_THREADS) return;
        int base = t4 * 4;
        int4 s4 = ((const int4*)seg_ids)[t4];
        int sv[5];
        sv[0] = (base == 0) ? -1 : seg_ids[base - 1];
        sv[1] = s4.x; sv[2] = s4.y; sv[3] = s4.z; sv[4] = s4.w;
        #pragma unroll
        for (int j = 0; j < 4; ++j) {
            int sp = sv[j], sc = sv[j + 1];
            if (sc > sp) {
                int b_lo = (sp + 5) / 5;   // first b with 5b > sp  (sp=-1 -> 0)
                int b_hi = sc / 5;         // last  b with 5b <= sc
                for (int b = b_lo; b <= b_hi; ++b) sample_start[b] = base + j;
            }
        }
        if (base + 4 == T_N) {
            // trailing (empty) samples: range starts at T
            for (int b = sv[4] / 5 + 1; b <= B_N; ++b) sample_start[b] = T_N;
        }
    }
}

// ---------------------------------------------------------------------------
// Kernel 2: one wave per sample. Range = [sample_start[b], sample_start[b+1]).
// Per-rating sums/counts via LDS atomics (5 slots/wave), then fused dot +
// bias + clip epilogue.
// ---------------------------------------------------------------------------
__global__ void sample_kernel(const int* __restrict__ user_idx,
                              const int* __restrict__ item_idx,
                              const int* __restrict__ flat_items,
                              const int* __restrict__ seg_ids,
                              const float* __restrict__ user_emb,
                              const float* __restrict__ item_emb,
                              const float* __restrict__ user_bias,
                              const float* __restrict__ item_bias,
                              const float* __restrict__ global_avg,
                              const float* __restrict__ rowsum,
                              const int* __restrict__ sample_start,
                              float* __restrict__ out) {
    __shared__ float s_sum[4][5];
    __shared__ int   s_cnt[4][5];

    int w    = threadIdx.x >> 6;
    int lane = threadIdx.x & 63;
    int b    = blockIdx.x * 4 + w;
    if (b >= B_N) return;

    if (lane < R_N) { s_sum[w][lane] = 0.f; s_cnt[w][lane] = 0; }
    __syncthreads();

    int lo = sample_start[b];
    int hi = sample_start[b + 1];
    int target = item_idx[b];

    for (int t = lo + lane; t < hi; t += 64) {
        int sg = seg_ids[t];
        int it = flat_items[t];
        if (it != target) {
            int r = sg - b * R_N;
            atomicAdd(&s_sum[w][r], rowsum[it]);
            atomicAdd(&s_cnt[w][r], 1);
        }
    }
    __syncthreads();

    float uu = 0.f;
    if (lane == 0) {
        #pragma unroll
        for (int r = 0; r < R_N; ++r) {
            int c = s_cnt[w][r];
            if (c > 0) uu += s_sum[w][r] / sqrtf((float)c);
        }
    }

    int u = user_idx[b];
    float ue = user_emb[(long)u * D_N + lane];
    float ie = item_emb[(long)target * D_N + lane];
    float dot = ue * ie;
    float isum = ie;
    #pragma unroll
    for (int off = 32; off >= 1; off >>= 1) {
        dot  += __shfl_xor(dot, off);
        isum += __shfl_xor(isum, off);
    }
    if (lane == 0) {
        float rui = dot + uu * isum + user_bias[u] + item_bias[target] + global_avg[0];
        rui = fminf(fmaxf(rui, 1.0f), 5.0f);
        out[b] = rui;
    }
}

extern "C" void kernel_launch(void* const* d_in, const int* in_sizes, int n_in,
                              void* d_out, int out_size, void* d_ws, size_t ws_size,
                              hipStream_t stream) {
    const int*   user_idx   = (const int*)d_in[0];
    const int*   item_idx   = (const int*)d_in[1];
    const int*   flat_items = (const int*)d_in[2];
    const int*   seg_ids    = (const int*)d_in[3];
    const float* user_emb   = (const float*)d_in[4];
    const float* item_emb   = (const float*)d_in[5];
    const float* Mr         = (const float*)d_in[6];
    const float* user_bias  = (const float*)d_in[7];
    const float* item_bias  = (const float*)d_in[8];
    const float* global_avg = (const float*)d_in[9];
    float* out = (float*)d_out;

    // ws layout: [rowsum: I_N floats][sample_start: B_N+1 ints]
    float* rowsum       = (float*)d_ws;
    int*   sample_start = (int*)(rowsum + I_N);

    prep_kernel<<<(K1_THREADS + 255) / 256, 256, 0, stream>>>(
        Mr, seg_ids, rowsum, sample_start);
    sample_kernel<<<B_N / 4, 256, 0, stream>>>(
        user_idx, item_idx, flat_items, seg_ids, user_emb, item_emb,
        user_bias, item_bias, global_avg, rowsum, sample_start, out);
}

// Round 4
// 141.066 us; speedup vs baseline: 1.1802x; 1.0441x over previous
//
#include <hip/hip_runtime.h>

#define U_N 100000
#define I_N 100000
#define D_N 64
#define B_N 16384
#define T_N 1638400
#define R_N 5

#define RS_THREADS (I_N * 16)    // rowsum part: 16 threads/row
#define BD_THREADS (T_N / 4)     // boundary part: 4 elements/thread
#define K1_THREADS (RS_THREADS + BD_THREADS)

// ---------------------------------------------------------------------------
// Kernel 1 (fused): (a) rowsum[i] = sum_d Mr[i][d]; (b) scatter sample range
// starts: sample_start[b] = first t with seg_ids[t] >= 5b, via linear
// transition scan of the sorted seg_ids.
// ---------------------------------------------------------------------------
__global__ void prep_kernel(const float* __restrict__ Mr,
                            const int* __restrict__ seg_ids,
                            float* __restrict__ rowsum,
                            int* __restrict__ sample_start) {
    int gtid = blockIdx.x * blockDim.x + threadIdx.x;
    if (gtid < RS_THREADS) {
        int row = gtid >> 4;
        int sub = gtid & 15;
        const float4* p = (const float4*)(Mr + (long)row * D_N);
        float4 v4 = p[sub];
        float v = v4.x + v4.y + v4.z + v4.w;
        v += __shfl_xor(v, 1);
        v += __shfl_xor(v, 2);
        v += __shfl_xor(v, 4);
        v += __shfl_xor(v, 8);
        if (sub == 0) rowsum[row] = v;
    } else {
        int t4 = gtid - RS_THREADS;
        if (t4 >= BD_THREADS) return;
        int base = t4 * 4;
        int4 s4 = ((const int4*)seg_ids)[t4];
        int sv[5];
        sv[0] = (base == 0) ? -1 : seg_ids[base - 1];
        sv[1] = s4.x; sv[2] = s4.y; sv[3] = s4.z; sv[4] = s4.w;
        #pragma unroll
        for (int j = 0; j < 4; ++j) {
            int sp = sv[j], sc = sv[j + 1];
            if (sc > sp) {
                int b_lo = (sp + 5) / 5;   // first b with 5b > sp  (sp=-1 -> 0)
                int b_hi = sc / 5;         // last  b with 5b <= sc
                for (int b = b_lo; b <= b_hi; ++b) sample_start[b] = base + j;
            }
        }
        if (base + 4 == T_N) {
            for (int b = sv[4] / 5 + 1; b <= B_N; ++b) sample_start[b] = T_N;
        }
    }
}

// ---------------------------------------------------------------------------
// Kernel 2: one wave per sample, no LDS. 4-deep unrolled loads for MLP,
// register accumulators (5 rating slots, predicated adds), xor-shuffle
// reduction, fused dot/bias/clip epilogue. Emb rows prefetched up front.
// ---------------------------------------------------------------------------
__global__ void sample_kernel(const int* __restrict__ user_idx,
                              const int* __restrict__ item_idx,
                              const int* __restrict__ flat_items,
                              const int* __restrict__ seg_ids,
                              const float* __restrict__ user_emb,
                              const float* __restrict__ item_emb,
                              const float* __restrict__ user_bias,
                              const float* __restrict__ item_bias,
                              const float* __restrict__ global_avg,
                              const float* __restrict__ rowsum,
                              const int* __restrict__ sample_start,
                              float* __restrict__ out) {
    int lane = threadIdx.x & 63;
    int b    = (blockIdx.x * blockDim.x + threadIdx.x) >> 6;
    if (b >= B_N) return;

    int u      = user_idx[b];
    int target = item_idx[b];
    // prefetch: issue the (likely HBM-miss) emb loads before the scan
    float ue = user_emb[(long)u * D_N + lane];
    float ie = item_emb[(long)target * D_N + lane];

    int lo = sample_start[b];
    int hi = sample_start[b + 1];
    int base5 = b * R_N;

    float acc[R_N] = {0.f, 0.f, 0.f, 0.f, 0.f};
    float cnt[R_N] = {0.f, 0.f, 0.f, 0.f, 0.f};

    for (int t0 = lo + lane; t0 < hi; t0 += 256) {
        int  sg[4], fi[4];
        bool ok[4];
        #pragma unroll
        for (int k = 0; k < 4; ++k) {
            int t = t0 + 64 * k;
            ok[k] = (t < hi);
            if (ok[k]) { sg[k] = seg_ids[t]; fi[k] = flat_items[t]; }
        }
        float rv[4];
        #pragma unroll
        for (int k = 0; k < 4; ++k) {
            if (ok[k]) rv[k] = rowsum[fi[k]];
        }
        #pragma unroll
        for (int k = 0; k < 4; ++k) {
            if (ok[k] && fi[k] != target) {
                int r = sg[k] - base5;
                #pragma unroll
                for (int rr = 0; rr < R_N; ++rr) {
                    if (r == rr) { acc[rr] += rv[k]; cnt[rr] += 1.f; }
                }
            }
        }
    }

    // cross-lane reduction of the 10 accumulators + dot/isum
    float dot = ue * ie;
    float isum = ie;
    #pragma unroll
    for (int off = 32; off >= 1; off >>= 1) {
        #pragma unroll
        for (int rr = 0; rr < R_N; ++rr) {
            acc[rr] += __shfl_xor(acc[rr], off);
            cnt[rr] += __shfl_xor(cnt[rr], off);
        }
        dot  += __shfl_xor(dot, off);
        isum += __shfl_xor(isum, off);
    }

    if (lane == 0) {
        float uu = 0.f;
        #pragma unroll
        for (int rr = 0; rr < R_N; ++rr) {
            if (cnt[rr] > 0.f) uu += acc[rr] / sqrtf(cnt[rr]);
        }
        float rui = dot + uu * isum + user_bias[u] + item_bias[target] + global_avg[0];
        rui = fminf(fmaxf(rui, 1.0f), 5.0f);
        out[b] = rui;
    }
}

extern "C" void kernel_launch(void* const* d_in, const int* in_sizes, int n_in,
                              void* d_out, int out_size, void* d_ws, size_t ws_size,
                              hipStream_t stream) {
    const int*   user_idx   = (const int*)d_in[0];
    const int*   item_idx   = (const int*)d_in[1];
    const int*   flat_items = (const int*)d_in[2];
    const int*   seg_ids    = (const int*)d_in[3];
    const float* user_emb   = (const float*)d_in[4];
    const float* item_emb   = (const float*)d_in[5];
    const float* Mr         = (const float*)d_in[6];
    const float* user_bias  = (const float*)d_in[7];
    const float* item_bias  = (const float*)d_in[8];
    const float* global_avg = (const float*)d_in[9];
    float* out = (float*)d_out;

    // ws layout: [rowsum: I_N floats][sample_start: B_N+1 ints]
    float* rowsum       = (float*)d_ws;
    int*   sample_start = (int*)(rowsum + I_N);

    prep_kernel<<<(K1_THREADS + 255) / 256, 256, 0, stream>>>(
        Mr, seg_ids, rowsum, sample_start);
    sample_kernel<<<B_N / 4, 256, 0, stream>>>(
        user_idx, item_idx, flat_items, seg_ids, user_emb, item_emb,
        user_bias, item_bias, global_avg, rowsum, sample_start, out);
}

// Round 5
// 136.526 us; speedup vs baseline: 1.2195x; 1.0333x over previous
//
#include <hip/hip_runtime.h>

#define U_N 100000
#define I_N 100000
#define D_N 64
#define B_N 16384
#define T_N 1638400
#define R_N 5
#define NSEG (B_N * R_N)         // 81920 segments

#define RS_THREADS (I_N * 16)    // rowsum part: 16 threads/row
#define BD_THREADS (T_N / 4)     // boundary part: 4 elements/thread
#define K1_THREADS (RS_THREADS + BD_THREADS)

// ---------------------------------------------------------------------------
// Kernel 1 (fused): (a) rowsum[i] = sum_d Mr[i][d]; (b) scatter SEGMENT range
// starts: seg_start[s] = first t with seg_ids[t] >= s, for s in [0, NSEG],
// via linear transition scan of the sorted seg_ids. Every entry written.
// ---------------------------------------------------------------------------
__global__ void prep_kernel(const float* __restrict__ Mr,
                            const int* __restrict__ seg_ids,
                            float* __restrict__ rowsum,
                            int* __restrict__ seg_start) {
    int gtid = blockIdx.x * blockDim.x + threadIdx.x;
    if (gtid < RS_THREADS) {
        int row = gtid >> 4;
        int sub = gtid & 15;
        const float4* p = (const float4*)(Mr + (long)row * D_N);
        float4 v4 = p[sub];
        float v = v4.x + v4.y + v4.z + v4.w;
        v += __shfl_xor(v, 1);
        v += __shfl_xor(v, 2);
        v += __shfl_xor(v, 4);
        v += __shfl_xor(v, 8);
        if (sub == 0) rowsum[row] = v;
    } else {
        int t4 = gtid - RS_THREADS;
        if (t4 >= BD_THREADS) return;
        int base = t4 * 4;
        int4 s4 = ((const int4*)seg_ids)[t4];
        int sv0 = (base == 0) ? -1 : seg_ids[base - 1];
        int sv1 = s4.x, sv2 = s4.y, sv3 = s4.z, sv4 = s4.w;
        for (int s = sv0 + 1; s <= sv1; ++s) seg_start[s] = base + 0;
        for (int s = sv1 + 1; s <= sv2; ++s) seg_start[s] = base + 1;
        for (int s = sv2 + 1; s <= sv3; ++s) seg_start[s] = base + 2;
        for (int s = sv3 + 1; s <= sv4; ++s) seg_start[s] = base + 3;
        if (base + 4 == T_N) {
            for (int s = sv4 + 1; s <= NSEG; ++s) seg_start[s] = T_N;
        }
    }
}

// ---------------------------------------------------------------------------
// Kernel 2: one wave per sample. Rating of element t is positional (from the
// 6 segment boundaries), so seg_ids is never read. Matches are counted with
// wave-uniform ballot+popcount (cold path), giving exact per-rating counts
// BEFORE accumulation; each lane then folds rowsum*rsqrt(cnt_r) into a
// single accumulator. Epilogue reduces 3 values.
// ---------------------------------------------------------------------------
__device__ __forceinline__ void count_matches(unsigned long long m, int tb,
                                              int e0, int e1, int e2, int e3,
                                              int e4, int e5, int* mcnt) {
    if (m) {
        int ea[6] = {e0, e1, e2, e3, e4, e5};
        #pragma unroll
        for (int r = 0; r < 5; ++r) {
            int a = ea[r] - tb;     a = a < 0 ? 0 : (a > 64 ? 64 : a);
            int bb = ea[r + 1] - tb; bb = bb < 0 ? 0 : (bb > 64 ? 64 : bb);
            if (bb > a) {
                unsigned long long hiM = (bb == 64) ? ~0ULL : ((1ULL << bb) - 1ULL);
                unsigned long long loM = (1ULL << a) - 1ULL;
                mcnt[r] += __popcll(m & hiM & ~loM);
            }
        }
    }
}

__global__ void sample_kernel(const int* __restrict__ user_idx,
                              const int* __restrict__ item_idx,
                              const int* __restrict__ flat_items,
                              const float* __restrict__ user_emb,
                              const float* __restrict__ item_emb,
                              const float* __restrict__ user_bias,
                              const float* __restrict__ item_bias,
                              const float* __restrict__ global_avg,
                              const float* __restrict__ rowsum,
                              const int* __restrict__ seg_start,
                              float* __restrict__ out) {
    int lane = threadIdx.x & 63;
    int b    = (blockIdx.x * blockDim.x + threadIdx.x) >> 6;
    if (b >= B_N) return;

    int u      = user_idx[b];
    int target = item_idx[b];
    // issue the (likely HBM-miss) emb loads first so they overlap the scan
    float ue = user_emb[(long)u * D_N + lane];
    float ie = item_emb[(long)target * D_N + lane];

    int e0 = seg_start[b * R_N + 0];
    int e1 = seg_start[b * R_N + 1];
    int e2 = seg_start[b * R_N + 2];
    int e3 = seg_start[b * R_N + 3];
    int e4 = seg_start[b * R_N + 4];
    int e5 = seg_start[b * R_N + 5];
    int lo = e0, hi = e5;

    // ---- pass 1: register-cache first 128 elements, count matches ----
    int t0 = lo + lane, t1 = lo + 64 + lane;
    bool ok0 = t0 < hi, ok1 = t1 < hi;
    int fi0 = -1, fi1 = -1;
    float rv0 = 0.f, rv1 = 0.f;
    if (ok0) fi0 = flat_items[t0];
    if (ok1) fi1 = flat_items[t1];
    if (ok0) rv0 = rowsum[fi0];
    if (ok1) rv1 = rowsum[fi1];

    int mcnt[5] = {0, 0, 0, 0, 0};
    unsigned long long m0 = __ballot(ok0 && fi0 == target);
    unsigned long long m1 = __ballot(ok1 && fi1 == target);
    count_matches(m0, lo,      e0, e1, e2, e3, e4, e5, mcnt);
    count_matches(m1, lo + 64, e0, e1, e2, e3, e4, e5, mcnt);
    // rare tail (range > 128): count matches only
    for (int tb = lo + 128; tb < hi; tb += 64) {
        int t = tb + lane;
        bool ok = t < hi;
        int fi = ok ? flat_items[t] : -1;
        unsigned long long m = __ballot(ok && fi == target);
        count_matches(m, tb, e0, e1, e2, e3, e4, e5, mcnt);
    }

    // ---- per-rating weights (all lanes identical) ----
    int c0 = (e1 - e0) - mcnt[0];
    int c1 = (e2 - e1) - mcnt[1];
    int c2 = (e3 - e2) - mcnt[2];
    int c3 = (e4 - e3) - mcnt[3];
    int c4 = (e5 - e4) - mcnt[4];
    float w0 = c0 > 0 ? rsqrtf((float)c0) : 0.f;
    float w1 = c1 > 0 ? rsqrtf((float)c1) : 0.f;
    float w2 = c2 > 0 ? rsqrtf((float)c2) : 0.f;
    float w3 = c3 > 0 ? rsqrtf((float)c3) : 0.f;
    float w4 = c4 > 0 ? rsqrtf((float)c4) : 0.f;

    // ---- pass 2: weighted accumulate (registers for first 128, reload tail) ----
    float acc = 0.f;
    if (ok0 && fi0 != target) {
        float w = t0 >= e1 ? (t0 >= e2 ? (t0 >= e3 ? (t0 >= e4 ? w4 : w3) : w2) : w1) : w0;
        acc += rv0 * w;
    }
    if (ok1 && fi1 != target) {
        float w = t1 >= e1 ? (t1 >= e2 ? (t1 >= e3 ? (t1 >= e4 ? w4 : w3) : w2) : w1) : w0;
        acc += rv1 * w;
    }
    for (int tb = lo + 128; tb < hi; tb += 64) {
        int t = tb + lane;
        if (t < hi) {
            int fi = flat_items[t];
            if (fi != target) {
                float rv = rowsum[fi];
                float w = t >= e1 ? (t >= e2 ? (t >= e3 ? (t >= e4 ? w4 : w3) : w2) : w1) : w0;
                acc += rv * w;
            }
        }
    }

    // ---- epilogue: reduce 3 values across the wave ----
    float dot = ue * ie;
    float isum = ie;
    #pragma unroll
    for (int off = 32; off >= 1; off >>= 1) {
        acc  += __shfl_xor(acc, off);
        dot  += __shfl_xor(dot, off);
        isum += __shfl_xor(isum, off);
    }
    if (lane == 0) {
        float rui = dot + acc * isum + user_bias[u] + item_bias[target] + global_avg[0];
        rui = fminf(fmaxf(rui, 1.0f), 5.0f);
        out[b] = rui;
    }
}

extern "C" void kernel_launch(void* const* d_in, const int* in_sizes, int n_in,
                              void* d_out, int out_size, void* d_ws, size_t ws_size,
                              hipStream_t stream) {
    const int*   user_idx   = (const int*)d_in[0];
    const int*   item_idx   = (const int*)d_in[1];
    const int*   flat_items = (const int*)d_in[2];
    const int*   seg_ids    = (const int*)d_in[3];
    const float* user_emb   = (const float*)d_in[4];
    const float* item_emb   = (const float*)d_in[5];
    const float* Mr         = (const float*)d_in[6];
    const float* user_bias  = (const float*)d_in[7];
    const float* item_bias  = (const float*)d_in[8];
    const float* global_avg = (const float*)d_in[9];
    float* out = (float*)d_out;

    // ws layout: [rowsum: I_N floats][seg_start: NSEG+1 ints]
    float* rowsum    = (float*)d_ws;
    int*   seg_start = (int*)(rowsum + I_N);

    prep_kernel<<<(K1_THREADS + 255) / 256, 256, 0, stream>>>(
        Mr, seg_ids, rowsum, seg_start);
    sample_kernel<<<B_N / 4, 256, 0, stream>>>(
        user_idx, item_idx, flat_items, user_emb, item_emb,
        user_bias, item_bias, global_avg, rowsum, seg_start, out);
}